// Round 11
// baseline (3186.536 us; speedup 1.0000x reference)
//
#include <hip/hip_runtime.h>

// ---------------------------------------------------------------------------
// SimpleGRU on MI355X (gfx950). Round 16: sc0 data-poll in the shared XCD L2.
//   Four falsifications (r9/r10/r13/r15 all 3.88-3.97us/step with different
//   release/store structures) isolate the invariant: DETECTION at system
//   scope (sc0sc1 load RT through the coherence fabric, ~1-2us contended).
//   Airtight evidence base: sc0 stores ARE visible to later sc0 loads from
//   other CUs in the same XCD (~4M successful one-shot exchanges in
//   r9/r10/r13/r15); r8's sc0 polls returned correct-but-stale L2 state
//   (producers stored sc0sc1 AROUND the L2) => sc0 loads bypass L1 and read
//   the shared L2. Untested combination: sc0 stores + sc0 DATA polling.
//   Now: producer = 16 sc0 fast stores + 16 sc0sc1 truth stores, all
//   fire-and-forget (r15: store traffic/drain is free). Consumer = r6-style
//   sentinel poll of its own fast row at sc0 (L2 RT ~300cy, no fabric); the
//   detecting round already holds the data (no flag hop, no read hop).
//   Safety: 64-round budget/step; 6 failed steps -> sticky downgrade to the
//   r6-PROVEN sc0sc1 truth-sentinel poll (truth written every step at system
//   scope => terminates; bounded ~2.9ms; no unproven unbounded loops).
//   Unbalanced dispatch / ring-reuse -> unchanged legacy r6 paths.
// ws: xg bf16 [512][1536][64] | truth [depth][64][512] f16 |
//     fast [8][depth][8][512] f16 | prog int[768]
// ---------------------------------------------------------------------------

typedef unsigned short ushort_t;
typedef short short8      __attribute__((ext_vector_type(8)));
typedef float floatx4     __attribute__((ext_vector_type(4)));
typedef unsigned int uintx4 __attribute__((ext_vector_type(4)));
typedef unsigned short ushort4v __attribute__((ext_vector_type(4)));
typedef _Float16 half8    __attribute__((ext_vector_type(8)));

#define SEQL 512
#define BATCH 64
#define EMBD 256
#define HID 512
#define G3 1536
#define NOUT 5
#define NGRP 8                     // one group per XCD (fast mode)
#define GRPB 8                     // batches per group (fast mode)
#define GSLOT 8192                 // fast ring slot: 8 x 512 x 2B
#define TSLOT 65536                // truth ring slot: 64 x 512 x 2B
#define RING2 131072               // truth + fast bytes per depth unit
#define XG_BYTES 100663296
#define PROGN 512                  // legacy prog area (includes regs at 384)
#define FLAGN 256                  // legacy flag area (zeroed, unused now)
#define ZERON (PROGN + FLAGN)      // 768 ints zeroed by init
#define LOCAL_BUDGET 64            // sc0 poll rounds per step before escape
#define BADSTEP_LIMIT 6            // escaped steps before sticky truth-only

__device__ __forceinline__ float bf2f(ushort_t v){
  union { unsigned u; float f; } x; x.u = ((unsigned)v) << 16; return x.f;
}
__device__ __forceinline__ ushort_t f2bf(float f){
  unsigned u = __float_as_uint(f);
  return (ushort_t)((u + 0x7FFFu + ((u >> 16) & 1u)) >> 16);
}
__device__ __forceinline__ float sigm(float x){
  x = fminf(fmaxf(x, -20.f), 20.f);
  return 1.f / (1.f + __expf(-x));
}
__device__ __forceinline__ float tanh_c(float x){
  x = fminf(fmaxf(x, -10.f), 10.f);
  float e = __expf(2.f * x);
  return (e - 1.f) / (e + 1.f);
}
__device__ __forceinline__ bool has_sent(half8 v){
  union { half8 h; unsigned u[4]; } x; x.h = v;
  bool b = false;
  #pragma unroll
  for (int i = 0; i < 4; ++i){
    b |= ((x.u[i] & 0xFFFFu) == 0xFFFFu);
    b |= ((x.u[i] >> 16) == 0xFFFFu);
  }
  return b;
}

// --- K0: sentinel-fill both rings at SYSTEM scope; zero prog+flags. ---
__global__ __launch_bounds__(256) void gru_init(char* __restrict__ rings,
                                                int* __restrict__ prog){
  size_t i = ((size_t)blockIdx.x * 256 + threadIdx.x) * 16;
  uintx4 s = {0xFFFFFFFFu, 0xFFFFFFFFu, 0xFFFFFFFFu, 0xFFFFFFFFu};
  const char* p = rings + i;
  asm volatile("global_store_dwordx4 %0, %1, off sc0 sc1" :: "v"(p), "v"(s) : "memory");
  if (blockIdx.x == 0){
    int z = 0;
    for (int k = threadIdx.x; k < ZERON; k += 256){
      asm volatile("global_store_dword %0, %1, off sc0 sc1"
                   :: "v"(prog + k), "v"(z) : "memory");
    }
  }
}

// --- K1: x_gates = emb[seq] @ w_ih^T + b_ih, bf16, layout [s][1536][64] ---
#define LDSIDX2(row, chunk) (((row) << 7) + ((((chunk) ^ ((row) & 7))) << 3))
__global__ __launch_bounds__(256) void gru_xgates(
    const int* __restrict__ seq, const float* __restrict__ emb,
    const float* __restrict__ w_ih, const float* __restrict__ b_ih,
    ushort_t* __restrict__ xg)
{
  __shared__ __align__(16) short lA[64 * 128];
  __shared__ __align__(16) short lB[64 * 128];
  const int tid   = threadIdx.x;
  const int sIdx  = blockIdx.x;
  const int nBase = blockIdx.y * 64;
  const int w    = tid >> 6;
  const int l    = tid & 63;
  const int l15  = l & 15;
  const int quad = l >> 4;
  floatx4 acc[4] = {};

  #pragma unroll
  for (int kp = 0; kp < 2; ++kp){
    __syncthreads();
    #pragma unroll
    for (int i = 0; i < 4; ++i){
      int lin = i * 256 + tid;
      int row = lin >> 4;
      int kc  = lin & 15;
      int kbase = kp * 128 + kc * 8;
      int token = seq[(sIdx << 6) + row];
      const float* srcA = emb  + (size_t)token * EMBD + kbase;
      const float* srcB = w_ih + (size_t)(nBase + row) * EMBD + kbase;
      floatx4 a0 = *(const floatx4*)(srcA);
      floatx4 a1 = *(const floatx4*)(srcA + 4);
      floatx4 b0 = *(const floatx4*)(srcB);
      floatx4 b1 = *(const floatx4*)(srcB + 4);
      short8 pa, pb;
      #pragma unroll
      for (int j = 0; j < 4; ++j){
        pa[j]     = (short)f2bf(a0[j]);
        pa[j + 4] = (short)f2bf(a1[j]);
        pb[j]     = (short)f2bf(b0[j]);
        pb[j + 4] = (short)f2bf(b1[j]);
      }
      *(short8*)&lA[LDSIDX2(row, kc)] = pa;
      *(short8*)&lB[LDSIDX2(row, kc)] = pb;
    }
    __syncthreads();
    #pragma unroll
    for (int kc = 0; kc < 4; ++kc){
      int chunk = kc * 4 + quad;
      short8 a = *(const short8*)&lA[LDSIDX2(w * 16 + l15, chunk)];
      #pragma unroll
      for (int s = 0; s < 4; ++s){
        short8 bf = *(const short8*)&lB[LDSIDX2(s * 16 + l15, chunk)];
        acc[s] = __builtin_amdgcn_mfma_f32_16x16x32_bf16(a, bf, acc[s], 0, 0, 0);
      }
    }
  }
  #pragma unroll
  for (int s = 0; s < 4; ++s){
    int g = nBase + s * 16 + l15;
    float bias = b_ih[g];
    ushort4v pk;
    #pragma unroll
    for (int r = 0; r < 4; ++r) pk[r] = f2bf(acc[s][r] + bias);
    *(ushort4v*)(xg + ((size_t)sIdx * G3 + g) * BATCH + (w * 16 + quad * 4)) = pk;
  }
}

// --- K2: recurrence. 256 blocks x 256 threads. ---
__global__ __launch_bounds__(256, 1) void gru_rec(
    const ushort_t* __restrict__ xg, const float* __restrict__ whh,
    const float* __restrict__ bhh, const int* __restrict__ lengths,
    char* __restrict__ truth, char* __restrict__ fastr,
    int* __restrict__ prog, int depth)
{
  __shared__ __align__(16) _Float16 wlds[48 * 64 * 8];   // 49,152 B (B-frags)
  __shared__ __align__(16) _Float16 hscr[4 * 256];       //  2,048 B (repack)
  __shared__ int s_grp, s_slc, s_fast;
  const int tid  = threadIdx.x;
  const int w    = tid >> 6;
  const int l    = tid & 63;
  const int l15  = l & 15;
  const int quad = l >> 4;

  // ---- rendezvous + XCD-affinity group formation ----
  int* regs = prog + 384;              // [0]=gcount, [1..8]=per-XCD counts
  if (tid == 0){
    unsigned xcd;
    asm volatile("s_getreg_b32 %0, hwreg(HW_REG_XCC_ID)" : "=s"(xcd));
    xcd &= 7u;
    int myx = atomicAdd(&regs[1 + xcd], 1);
    asm volatile("s_waitcnt vmcnt(0)" ::: "memory");  // xcd count visible first
    int gt = atomicAdd(&regs[0], 1);
    int v;
    do {
      asm volatile("s_sleep 1" ::: "memory");
      asm volatile("global_load_dword %0, %1, off sc0 sc1\n\t"
                   "s_waitcnt vmcnt(0)"
                   : "=v"(v) : "v"(&regs[0]) : "memory");
    } while (v < 256);
    int ok = 1;
    #pragma unroll
    for (int x = 0; x < 8; ++x){
      int c;
      asm volatile("global_load_dword %0, %1, off sc0 sc1\n\t"
                   "s_waitcnt vmcnt(0)"
                   : "=v"(c) : "v"(&regs[1 + x]) : "memory");
      ok &= (c == 32);
    }
    s_fast = ok;
    s_grp  = ok ? (int)xcd : 0;
    s_slc  = ok ? (myx & 31) : gt;
  }
  __syncthreads();
  const int fast = s_fast;
  const int grp  = s_grp;
  const int g0   = s_slc;
  if (!fast && g0 >= 32) return;       // fallback: only 32 blocks participate
  const int g = g0 & 31;               // hidden slice [g*16, g*16+16)
  const int j = g * 16 + l15;          // this lane's hidden unit

  // ---- setup: 48 W_hh rows f32->f16 into B-frag LDS (all 4 waves) ----
  #pragma unroll
  for (int i = 0; i < 12; ++i){
    int p  = i * 4 + w;                 // 0..47
    int G  = p >> 4;                    // gate (0=r,1=z,2=n)
    int ks = p & 15;                    // K-step
    const float* src = whh + (size_t)(G * HID + j) * HID + ks * 32 + quad * 8;
    floatx4 f0 = *(const floatx4*)(src);
    floatx4 f1 = *(const floatx4*)(src + 4);
    half8 hv;
    #pragma unroll
    for (int q = 0; q < 4; ++q){ hv[q] = (_Float16)f0[q]; hv[q + 4] = (_Float16)f1[q]; }
    *(half8*)&wlds[((size_t)p * 64 + l) * 8] = hv;
  }
  __syncthreads();
  if (fast && tid >= 64) return;       // fast mode: wave 0 runs alone

  char* fastb = fastr + (size_t)grp * depth * GSLOT;
  const int locb = fast ? ((quad & 1) * 4) : (quad * 4);  // wave-local batch base
  const int gb   = fast ? (grp * GRPB + locb) : (w * 16 + locb);  // global batch
  const int arow = l15 & 7;                                // fast ring A-row
  const int trow = fast ? (grp * GRPB + (l15 & 7)) : (w * 16 + l15); // truth row
  const float bhR = bhh[j], bhZ = bhh[HID + j], bhN = bhh[2 * HID + j];
  int   len[4];
  float h[4];
  #pragma unroll
  for (int r = 0; r < 4; ++r){ len[r] = lengths[gb + r]; h[r] = 0.f; }
  const int Lmax  = lengths[0];        // global max: all blocks run to Lmax
  const int mask  = depth - 1;
  const bool reuse = (depth < Lmax);
  const int fastpath = fast && !reuse; // sc0 L2 data-poll protocol
  int localok = fastpath;              // sticky: sc0 poll enabled
  int badsteps = 0;
  int cmin = 0;

  for (int t = 0; t < Lmax; ++t){
    // 0) ring-reuse guard (legacy modes only; dead when depth >= Lmax)
    if (reuse && t >= depth){
      int target = t - depth + 2;
      if (cmin < target){
        int tgt2 = target + 4;
        if (fast){
          const int* pp = prog + 128 + grp * 32 + (l & 31);
          while (true){
            int p0;
            asm volatile("global_load_dword %0, %1, off sc0 sc1\n\t"
                         "s_waitcnt vmcnt(0)"
                         : "=v"(p0) : "v"(pp) : "memory");
            if (__all(p0 >= tgt2)) break;
            __builtin_amdgcn_s_sleep(2);
          }
        } else {
          while (true){
            int p0, p1;
            asm volatile("global_load_dword %0, %2, off sc0 sc1\n\t"
                         "global_load_dword %1, %3, off sc0 sc1\n\t"
                         "s_waitcnt vmcnt(0)"
                         : "=v"(p0), "=v"(p1) : "v"(prog + l), "v"(prog + 64 + l)
                         : "memory");
            if (__all(p0 >= tgt2 && p1 >= tgt2)) break;
            __builtin_amdgcn_s_sleep(2);
          }
        }
        cmin = tgt2;
      }
    }

    // 1) xg prefetch (independent of h; latency overlaps the poll below)
    const ushort_t* xt = xg + (size_t)t * G3 * BATCH;
    ushort4v xR = __builtin_nontemporal_load(
        (const ushort4v*)(xt + (size_t)(          j) * BATCH + gb));
    ushort4v xZ = __builtin_nontemporal_load(
        (const ushort4v*)(xt + (size_t)(HID     + j) * BATCH + gb));
    ushort4v xN = __builtin_nontemporal_load(
        (const ushort4v*)(xt + (size_t)(2 * HID + j) * BATCH + gb));

    // 2) consume h(t-1)
    floatx4 aR = {0.f,0.f,0.f,0.f}, aZ = {0.f,0.f,0.f,0.f}, aN = {0.f,0.f,0.f,0.f};
    if (t > 0){
      const int slotp = (t - 1) & mask;
      const char* rowf = fastb + (size_t)slotp * GSLOT
                       + (size_t)arow * 1024 + quad * 16;
      const char* rowt = truth + (size_t)slotp * TSLOT
                       + (size_t)trow * 1024 + quad * 16;
      half8 aF[16];
      bool got = false;
      if (localok){
        // 2a-LOCAL: sentinel-poll OWN data at sc0. sc0 loads bypass L1 and
        //     read the shared XCD L2 (r8 behavior); producer's sc0 stores
        //     land there (~4M proven one-shot exchanges). The detecting
        //     round already holds the data — no flag hop, no read hop,
        //     no fabric. Budget-bounded; escape below is r6-proven.
        int rounds = 0;
        while (true){
          #pragma unroll
          for (int ks = 0; ks < 16; ++ks){
            const char* pa = rowf + ks * 64;
            asm volatile("global_load_dwordx4 %0, %1, off sc0"
                         : "=v"(aF[ks]) : "v"(pa) : "memory");
          }
          asm volatile("s_waitcnt vmcnt(0)"
                       : "+v"(aF[0]),  "+v"(aF[1]),  "+v"(aF[2]),  "+v"(aF[3]),
                         "+v"(aF[4]),  "+v"(aF[5]),  "+v"(aF[6]),  "+v"(aF[7]),
                         "+v"(aF[8]),  "+v"(aF[9]),  "+v"(aF[10]), "+v"(aF[11]),
                         "+v"(aF[12]), "+v"(aF[13]), "+v"(aF[14]), "+v"(aF[15])
                       :: "memory");
          bool bad = false;
          #pragma unroll
          for (int ks = 0; ks < 16; ++ks) bad |= has_sent(aF[ks]);
          if (!__any(bad)){ got = true; break; }
          if (++rounds >= LOCAL_BUDGET) break;
          if (rounds > 8) __builtin_amdgcn_s_sleep(1);
        }
        if (!got && ++badsteps >= BADSTEP_LIMIT) localok = 0;  // sticky
      }
      if (!got){
        // 2a-TRUTH: r6-proven self-synchronizing sc0sc1 sentinel poll.
        // (fastpath producers write truth every step at system scope ->
        //  guaranteed to terminate; legacy path identical to r6.)
        int rounds = 0;
        while (true){
          if (rounds){
            if (rounds > 64) __builtin_amdgcn_s_sleep(8);
            else             __builtin_amdgcn_s_sleep(2);
          }
          ++rounds;
          #pragma unroll
          for (int ks = 0; ks < 16; ++ks){
            const char* pa = rowt + ks * 64;
            asm volatile("global_load_dwordx4 %0, %1, off sc0 sc1"
                         : "=v"(aF[ks]) : "v"(pa) : "memory");
          }
          asm volatile("s_waitcnt vmcnt(0)"
                       : "+v"(aF[0]),  "+v"(aF[1]),  "+v"(aF[2]),  "+v"(aF[3]),
                         "+v"(aF[4]),  "+v"(aF[5]),  "+v"(aF[6]),  "+v"(aF[7]),
                         "+v"(aF[8]),  "+v"(aF[9]),  "+v"(aF[10]), "+v"(aF[11]),
                         "+v"(aF[12]), "+v"(aF[13]), "+v"(aF[14]), "+v"(aF[15])
                       :: "memory");
          bool bad = false;
          #pragma unroll
          for (int ks = 0; ks < 16; ++ks) bad |= has_sent(aF[ks]);
          if (!__any(bad)) break;
        }
      }
      #pragma unroll
      for (int ks = 0; ks < 16; ++ks){
        half8 a  = aF[ks];
        half8 b0 = *(const half8*)&wlds[((size_t)(0 * 16 + ks) * 64 + l) * 8];
        half8 b1 = *(const half8*)&wlds[((size_t)(1 * 16 + ks) * 64 + l) * 8];
        half8 b2 = *(const half8*)&wlds[((size_t)(2 * 16 + ks) * 64 + l) * 8];
        aR = __builtin_amdgcn_mfma_f32_16x16x32_f16(a, b0, aR, 0, 0, 0);
        aZ = __builtin_amdgcn_mfma_f32_16x16x32_f16(a, b1, aZ, 0, 0, 0);
        aN = __builtin_amdgcn_mfma_f32_16x16x32_f16(a, b2, aN, 0, 0, 0);
      }
      // restore sentinels on consumed truth chunks (legacy reuse only)
      if (reuse){
        uintx4 sv = {0xFFFFFFFFu, 0xFFFFFFFFu, 0xFFFFFFFFu, 0xFFFFFFFFu};
        if (!fast || l15 < 8){
          #pragma unroll
          for (int ks = 0; ks < 16; ++ks){
            const char* pt = rowt + ks * 64;
            asm volatile("global_store_dwordx4 %0, %1, off sc0 sc1"
                         :: "v"(pt), "v"(sv) : "memory");
          }
        }
      }
    }

    // 3) gates + h update (f32 carry); mirrored quads duplicate harmlessly
    #pragma unroll
    for (int r = 0; r < 4; ++r){
      float rr = sigm(bf2f(xR[r]) + aR[r] + bhR);
      float zz = sigm(bf2f(xZ[r]) + aZ[r] + bhZ);
      float nn = tanh_c(bf2f(xN[r]) + rr * (aN[r] + bhN));
      float hn = (1.f - zz) * nn + zz * h[r];
      h[r] = (t < len[r]) ? hn : h[r];
    }

    // 4) intra-wave repack via LDS, then publish h(t)
    _Float16* scr = hscr + w * 256;
    if (!fast || quad < 2){
      #pragma unroll
      for (int r = 0; r < 4; ++r) scr[(locb + r) * 16 + l15] = (_Float16)h[r];
    }
    asm volatile("s_waitcnt lgkmcnt(0)" ::: "memory");   // wave-local DS order
    if (fastpath){
      // release: 16 sc0 fast stores (land in shared XCD L2) + 16 sc0sc1
      // truth stores (escape feed + K3). ALL fire-and-forget: no vmcnt, no
      // flag — r15 proved store traffic/drain is free; the next step's poll
      // drains the queue while the data propagates.
      if (l < 16){
        int bl = l >> 1;
        int hc = l & 1;
        half8 ch = *(const half8*)&scr[bl * 16 + hc * 8];
        const char* df = fastb + (size_t)(t & mask) * GSLOT
                       + (size_t)bl * 1024 + (size_t)g * 32 + (size_t)hc * 16;
        asm volatile("global_store_dwordx4 %0, %1, off sc0"
                     :: "v"(df), "v"(ch) : "memory");
        const char* dt = truth + (size_t)(t & mask) * TSLOT
                       + (size_t)(grp * GRPB + bl) * 1024
                       + (size_t)g * 32 + (size_t)hc * 16;
        asm volatile("global_store_dwordx4 %0, %1, off sc0 sc1"
                     :: "v"(dt), "v"(ch) : "memory");
      }
    } else {
      const int pubN = fast ? 16 : 32;
      if (l < pubN){
        int bl = l >> 1;
        int hc = l & 1;
        half8 ch = *(const half8*)&scr[bl * 16 + hc * 8];
        int gbatch = fast ? (grp * GRPB + bl) : (w * 16 + bl);
        const char* dt = truth + (size_t)(t & mask) * TSLOT
                       + (size_t)gbatch * 1024 + (size_t)g * 32 + (size_t)hc * 16;
        asm volatile("global_store_dwordx4 %0, %1, off sc0 sc1"
                     :: "v"(dt), "v"(ch) : "memory");
      }
      // 5) coarse progress publish (reuse mode only), ordered after restores
      if (reuse && ((t & 7) == 7)){
        asm volatile("s_waitcnt vmcnt(0)" ::: "memory");
        if (l == 0){
          int pv = t + 1;
          const int* pp = fast ? (prog + 128 + grp * 32 + g) : (prog + w * 32 + g);
          asm volatile("global_store_dword %0, %1, off sc0 sc1"
                       :: "v"(pp), "v"(pv) : "memory");
        }
      }
    }
  }
}

// --- K3: logits + log_softmax from truth slot (Lmax-1). 64 blocks x 64. ---
__global__ __launch_bounds__(64) void gru_out(
    const char* __restrict__ truth, const int* __restrict__ lengths,
    const float* __restrict__ wout, const float* __restrict__ bout,
    float* __restrict__ out, int depth)
{
  const int b = blockIdx.x, l = threadIdx.x;
  const int Lmax = lengths[0];
  const _Float16* h = (const _Float16*)(truth
      + (size_t)((Lmax - 1) & (depth - 1)) * TSLOT + (size_t)b * 1024);
  half8 hv = *(const half8*)(h + l * 8);
  float p[NOUT];
  #pragma unroll
  for (int o = 0; o < NOUT; ++o){
    const float* wr = wout + o * HID + l * 8;
    float a = 0.f;
    #pragma unroll
    for (int i = 0; i < 8; ++i) a += wr[i] * (float)hv[i];
    #pragma unroll
    for (int d = 32; d >= 1; d >>= 1) a += __shfl_down(a, d, 64);
    p[o] = a;
  }
  if (l == 0){
    float lg[NOUT], m = -1e30f;
    #pragma unroll
    for (int o = 0; o < NOUT; ++o){
      float v = p[o] + bout[o];
      if (!(v == v)) v = -1.0f;
      lg[o] = v; m = fmaxf(m, v);
    }
    float ssum = 0.f;
    #pragma unroll
    for (int o = 0; o < NOUT; ++o) ssum += __expf(lg[o] - m);
    float ls = __logf(ssum);
    #pragma unroll
    for (int o = 0; o < NOUT; ++o) out[b * NOUT + o] = lg[o] - m - ls;
  }
}

extern "C" void kernel_launch(void* const* d_in, const int* in_sizes, int n_in,
                              void* d_out, int out_size, void* d_ws, size_t ws_size,
                              hipStream_t stream) {
  (void)in_sizes; (void)n_in; (void)out_size;
  const int*   seq     = (const int*)d_in[0];
  const int*   lengths = (const int*)d_in[1];
  const float* emb     = (const float*)d_in[2];
  const float* w_ih    = (const float*)d_in[3];
  const float* w_hh    = (const float*)d_in[4];
  const float* b_ih    = (const float*)d_in[5];
  const float* b_hh    = (const float*)d_in[6];
  const float* w_out   = (const float*)d_in[7];
  const float* b_out   = (const float*)d_in[8];
  float*       outp    = (float*)d_out;

  // ring depth: largest power of two in [16, 512] such that both rings
  // (depth * 128 KiB) + prog fit the workspace after xg.
  size_t avail = (ws_size > (size_t)XG_BYTES + 32768)
               ? ws_size - (size_t)XG_BYTES - 32768 : 0;
  int depth = 16;
  while (depth < 512 && ((size_t)(depth << 1) * RING2) <= avail) depth <<= 1;

  char* ws = (char*)d_ws;
  ushort_t* xg    = (ushort_t*)ws;                                 // 100,663,296 B
  char*     truth = ws + XG_BYTES;                                 // depth*65,536 B
  char*     fastr = truth + (size_t)depth * TSLOT;                 // depth*65,536 B
  int*      prog  = (int*)(fastr + (size_t)depth * TSLOT);         // 768 ints

  gru_init<<<depth * 32, 256, 0, stream>>>(truth, prog);
  dim3 g1(SEQL, G3 / 64);
  gru_xgates<<<g1, 256, 0, stream>>>(seq, emb, w_ih, b_ih, xg);
  gru_rec<<<256, 256, 0, stream>>>(xg, w_hh, b_hh, lengths, truth, fastr, prog, depth);
  gru_out<<<BATCH, 64, 0, stream>>>(truth, lengths, w_out, b_out, outp, depth);
}

// Round 12
// 2495.895 us; speedup vs baseline: 1.2767x; 1.2767x over previous
//
#include <hip/hip_runtime.h>

// ---------------------------------------------------------------------------
// SimpleGRU on MI355X (gfx950). Round 17: replica-rotation sc0 L2 data-poll.
//   Closed mechanism model from r8..r16:
//     - sc0 load, L1 miss  -> reads shared XCD L2 (first touch ALWAYS correct;
//       ~4M proven one-shot exchanges in r9/r10/r13/r15).
//     - sc0 load, re-poll  -> served by consumer L1 (cached sentinel) forever
//       (r8 + r16 failures).
//     - atomics (any)      -> device-scope at the fabric (m20; r13 == r10 null).
//     - anything sc0sc1    -> fabric RT ~1.5-2us contended => 3.9us/step floor
//       (r9/r10/r13/r15 all identical).
//   Therefore: the ONLY sub-fabric channel is sc0-store -> sc0 FIRST-TOUCH
//   load. Replica rotation makes every poll round a first touch: producer
//   writes h(t) to R replicas (fire-and-forget sc0; r15 proved stores free);
//   consumer polls round r at replica min(r,R-1) -> fresh address -> L1 miss
//   -> current L2 state. Detection ~0.1us/round, no fabric, no flags, no
//   vmcnt, no atomics.
//   Safety: replica loop bounded at R rounds -> truth sc0sc1 sentinel poll
//   (r6-proven; truth written every step in fastpath); 6 bad steps -> sticky
//   truth-always (bounded ~3ms). Unbalanced dispatch / small ws -> legacy r6.
// ws: xg bf16 [512][1536][64] | truth [512][64][512] f16 (32MB) |
//     fast [R][512][8grp][8][512] f16 (R x 32MB) | prog int[768]
// ---------------------------------------------------------------------------

typedef unsigned short ushort_t;
typedef short short8      __attribute__((ext_vector_type(8)));
typedef float floatx4     __attribute__((ext_vector_type(4)));
typedef unsigned int uintx4 __attribute__((ext_vector_type(4)));
typedef unsigned short ushort4v __attribute__((ext_vector_type(4)));
typedef _Float16 half8    __attribute__((ext_vector_type(8)));

#define SEQL 512
#define BATCH 64
#define EMBD 256
#define HID 512
#define G3 1536
#define NOUT 5
#define NGRP 8                       // one group per XCD (fast mode)
#define GRPB 8                       // batches per group (fast mode)
#define TSLOT 65536                  // truth ring slot: 64 x 512 x 2B
#define RING2 131072                 // legacy sizing unit (truth+fast per depth)
#define REPSTRIDE (512ull * 65536ull) // one replica plane: 512 slots x 64KB
#define XG_BYTES 100663296
#define PROGN 512
#define FLAGN 256
#define ZERON (PROGN + FLAGN)        // 768 ints zeroed by init
#define BADSTEP_LIMIT 6

__device__ __forceinline__ float bf2f(ushort_t v){
  union { unsigned u; float f; } x; x.u = ((unsigned)v) << 16; return x.f;
}
__device__ __forceinline__ ushort_t f2bf(float f){
  unsigned u = __float_as_uint(f);
  return (ushort_t)((u + 0x7FFFu + ((u >> 16) & 1u)) >> 16);
}
__device__ __forceinline__ float sigm(float x){
  x = fminf(fmaxf(x, -20.f), 20.f);
  return 1.f / (1.f + __expf(-x));
}
__device__ __forceinline__ float tanh_c(float x){
  x = fminf(fmaxf(x, -10.f), 10.f);
  float e = __expf(2.f * x);
  return (e - 1.f) / (e + 1.f);
}
__device__ __forceinline__ bool has_sent(half8 v){
  union { half8 h; unsigned u[4]; } x; x.h = v;
  bool b = false;
  #pragma unroll
  for (int i = 0; i < 4; ++i){
    b |= ((x.u[i] & 0xFFFFu) == 0xFFFFu);
    b |= ((x.u[i] >> 16) == 0xFFFFu);
  }
  return b;
}

// --- K0: sentinel-fill truth+fast at SYSTEM scope; zero prog. Grid covers
//     the ring region exactly (host computes block count). ---
__global__ __launch_bounds__(256) void gru_init(char* __restrict__ rings,
                                                int* __restrict__ prog){
  size_t i = ((size_t)blockIdx.x * 256 + threadIdx.x) * 16;
  uintx4 s = {0xFFFFFFFFu, 0xFFFFFFFFu, 0xFFFFFFFFu, 0xFFFFFFFFu};
  const char* p = rings + i;
  asm volatile("global_store_dwordx4 %0, %1, off sc0 sc1" :: "v"(p), "v"(s) : "memory");
  if (blockIdx.x == 0){
    int z = 0;
    for (int k = threadIdx.x; k < ZERON; k += 256){
      asm volatile("global_store_dword %0, %1, off sc0 sc1"
                   :: "v"(prog + k), "v"(z) : "memory");
    }
  }
}

// --- K1: x_gates = emb[seq] @ w_ih^T + b_ih, bf16, layout [s][1536][64] ---
#define LDSIDX2(row, chunk) (((row) << 7) + ((((chunk) ^ ((row) & 7))) << 3))
__global__ __launch_bounds__(256) void gru_xgates(
    const int* __restrict__ seq, const float* __restrict__ emb,
    const float* __restrict__ w_ih, const float* __restrict__ b_ih,
    ushort_t* __restrict__ xg)
{
  __shared__ __align__(16) short lA[64 * 128];
  __shared__ __align__(16) short lB[64 * 128];
  const int tid   = threadIdx.x;
  const int sIdx  = blockIdx.x;
  const int nBase = blockIdx.y * 64;
  const int w    = tid >> 6;
  const int l    = tid & 63;
  const int l15  = l & 15;
  const int quad = l >> 4;
  floatx4 acc[4] = {};

  #pragma unroll
  for (int kp = 0; kp < 2; ++kp){
    __syncthreads();
    #pragma unroll
    for (int i = 0; i < 4; ++i){
      int lin = i * 256 + tid;
      int row = lin >> 4;
      int kc  = lin & 15;
      int kbase = kp * 128 + kc * 8;
      int token = seq[(sIdx << 6) + row];
      const float* srcA = emb  + (size_t)token * EMBD + kbase;
      const float* srcB = w_ih + (size_t)(nBase + row) * EMBD + kbase;
      floatx4 a0 = *(const floatx4*)(srcA);
      floatx4 a1 = *(const floatx4*)(srcA + 4);
      floatx4 b0 = *(const floatx4*)(srcB);
      floatx4 b1 = *(const floatx4*)(srcB + 4);
      short8 pa, pb;
      #pragma unroll
      for (int j = 0; j < 4; ++j){
        pa[j]     = (short)f2bf(a0[j]);
        pa[j + 4] = (short)f2bf(a1[j]);
        pb[j]     = (short)f2bf(b0[j]);
        pb[j + 4] = (short)f2bf(b1[j]);
      }
      *(short8*)&lA[LDSIDX2(row, kc)] = pa;
      *(short8*)&lB[LDSIDX2(row, kc)] = pb;
    }
    __syncthreads();
    #pragma unroll
    for (int kc = 0; kc < 4; ++kc){
      int chunk = kc * 4 + quad;
      short8 a = *(const short8*)&lA[LDSIDX2(w * 16 + l15, chunk)];
      #pragma unroll
      for (int s = 0; s < 4; ++s){
        short8 bf = *(const short8*)&lB[LDSIDX2(s * 16 + l15, chunk)];
        acc[s] = __builtin_amdgcn_mfma_f32_16x16x32_bf16(a, bf, acc[s], 0, 0, 0);
      }
    }
  }
  #pragma unroll
  for (int s = 0; s < 4; ++s){
    int g = nBase + s * 16 + l15;
    float bias = b_ih[g];
    ushort4v pk;
    #pragma unroll
    for (int r = 0; r < 4; ++r) pk[r] = f2bf(acc[s][r] + bias);
    *(ushort4v*)(xg + ((size_t)sIdx * G3 + g) * BATCH + (w * 16 + quad * 4)) = pk;
  }
}

// --- K2: recurrence. 256 blocks x 256 threads. ---
__global__ __launch_bounds__(256, 1) void gru_rec(
    const ushort_t* __restrict__ xg, const float* __restrict__ whh,
    const float* __restrict__ bhh, const int* __restrict__ lengths,
    char* __restrict__ truth, char* __restrict__ fastr,
    int* __restrict__ prog, int depth, int R)
{
  __shared__ __align__(16) _Float16 wlds[48 * 64 * 8];   // 49,152 B (B-frags)
  __shared__ __align__(16) _Float16 hscr[4 * 256];       //  2,048 B (repack)
  __shared__ int s_grp, s_slc, s_fast;
  const int tid  = threadIdx.x;
  const int w    = tid >> 6;
  const int l    = tid & 63;
  const int l15  = l & 15;
  const int quad = l >> 4;

  // ---- rendezvous + XCD-affinity group formation ----
  int* regs = prog + 384;              // [0]=gcount, [1..8]=per-XCD counts
  if (tid == 0){
    unsigned xcd;
    asm volatile("s_getreg_b32 %0, hwreg(HW_REG_XCC_ID)" : "=s"(xcd));
    xcd &= 7u;
    int myx = atomicAdd(&regs[1 + xcd], 1);
    asm volatile("s_waitcnt vmcnt(0)" ::: "memory");  // xcd count visible first
    int gt = atomicAdd(&regs[0], 1);
    int v;
    do {
      asm volatile("s_sleep 1" ::: "memory");
      asm volatile("global_load_dword %0, %1, off sc0 sc1\n\t"
                   "s_waitcnt vmcnt(0)"
                   : "=v"(v) : "v"(&regs[0]) : "memory");
    } while (v < 256);
    int ok = 1;
    #pragma unroll
    for (int x = 0; x < 8; ++x){
      int c;
      asm volatile("global_load_dword %0, %1, off sc0 sc1\n\t"
                   "s_waitcnt vmcnt(0)"
                   : "=v"(c) : "v"(&regs[1 + x]) : "memory");
      ok &= (c == 32);
    }
    s_fast = ok;
    s_grp  = ok ? (int)xcd : 0;
    s_slc  = ok ? (myx & 31) : gt;
  }
  __syncthreads();
  const int fast = s_fast;
  const int grp  = s_grp;
  const int g0   = s_slc;
  if (!fast && g0 >= 32) return;       // fallback: only 32 blocks participate
  const int g = g0 & 31;               // hidden slice [g*16, g*16+16)
  const int j = g * 16 + l15;          // this lane's hidden unit

  // ---- setup: 48 W_hh rows f32->f16 into B-frag LDS (all 4 waves) ----
  #pragma unroll
  for (int i = 0; i < 12; ++i){
    int p  = i * 4 + w;                 // 0..47
    int G  = p >> 4;                    // gate (0=r,1=z,2=n)
    int ks = p & 15;                    // K-step
    const float* src = whh + (size_t)(G * HID + j) * HID + ks * 32 + quad * 8;
    floatx4 f0 = *(const floatx4*)(src);
    floatx4 f1 = *(const floatx4*)(src + 4);
    half8 hv;
    #pragma unroll
    for (int q = 0; q < 4; ++q){ hv[q] = (_Float16)f0[q]; hv[q + 4] = (_Float16)f1[q]; }
    *(half8*)&wlds[((size_t)p * 64 + l) * 8] = hv;
  }
  __syncthreads();
  if (fast && tid >= 64) return;       // fast mode: wave 0 runs alone

  const int locb = fast ? ((quad & 1) * 4) : (quad * 4);  // wave-local batch base
  const int gb   = fast ? (grp * GRPB + locb) : (w * 16 + locb);  // global batch
  const int arow = l15 & 7;                                // fast ring A-row
  const int trow = fast ? (grp * GRPB + (l15 & 7)) : (w * 16 + l15); // truth row
  const float bhR = bhh[j], bhZ = bhh[HID + j], bhN = bhh[2 * HID + j];
  int   len[4];
  float h[4];
  #pragma unroll
  for (int r = 0; r < 4; ++r){ len[r] = lengths[gb + r]; h[r] = 0.f; }
  const int Lmax  = lengths[0];        // global max: all blocks run to Lmax
  const int mask  = depth - 1;
  const bool reuse = (depth < Lmax);
  const int fastpath = fast && !reuse && (R >= 2);  // replica-rotation protocol
  int localok = fastpath;              // sticky: replica poll enabled
  int badsteps = 0;
  int cmin = 0;

  for (int t = 0; t < Lmax; ++t){
    // 0) ring-reuse guard (legacy modes only; dead when depth >= Lmax)
    if (reuse && t >= depth){
      int target = t - depth + 2;
      if (cmin < target){
        int tgt2 = target + 4;
        if (fast){
          const int* pp = prog + 128 + grp * 32 + (l & 31);
          while (true){
            int p0;
            asm volatile("global_load_dword %0, %1, off sc0 sc1\n\t"
                         "s_waitcnt vmcnt(0)"
                         : "=v"(p0) : "v"(pp) : "memory");
            if (__all(p0 >= tgt2)) break;
            __builtin_amdgcn_s_sleep(2);
          }
        } else {
          while (true){
            int p0, p1;
            asm volatile("global_load_dword %0, %2, off sc0 sc1\n\t"
                         "global_load_dword %1, %3, off sc0 sc1\n\t"
                         "s_waitcnt vmcnt(0)"
                         : "=v"(p0), "=v"(p1) : "v"(prog + l), "v"(prog + 64 + l)
                         : "memory");
            if (__all(p0 >= tgt2 && p1 >= tgt2)) break;
            __builtin_amdgcn_s_sleep(2);
          }
        }
        cmin = tgt2;
      }
    }

    // 1) xg prefetch (independent of h; latency overlaps the poll below)
    const ushort_t* xt = xg + (size_t)t * G3 * BATCH;
    ushort4v xR = __builtin_nontemporal_load(
        (const ushort4v*)(xt + (size_t)(          j) * BATCH + gb));
    ushort4v xZ = __builtin_nontemporal_load(
        (const ushort4v*)(xt + (size_t)(HID     + j) * BATCH + gb));
    ushort4v xN = __builtin_nontemporal_load(
        (const ushort4v*)(xt + (size_t)(2 * HID + j) * BATCH + gb));

    // 2) consume h(t-1)
    floatx4 aR = {0.f,0.f,0.f,0.f}, aZ = {0.f,0.f,0.f,0.f}, aN = {0.f,0.f,0.f,0.f};
    if (t > 0){
      const int slotp = (t - 1) & mask;
      const char* rowt = truth + (size_t)slotp * TSLOT
                       + (size_t)trow * 1024 + quad * 16;
      half8 aF[16];
      bool got = false;
      if (localok){
        // 2a-LOCAL: replica-rotation poll. Round r reads replica min(r,R-1)
        //     — a FRESH address for r < R — guaranteed L1 miss — current
        //     shared-L2 state. Detects the moment producers' sc0 stores
        //     land. Hard-bounded at R rounds; no fabric ops.
        const size_t rbase = (size_t)slotp * TSLOT + (size_t)grp * 8192
                           + (size_t)arow * 1024 + (size_t)quad * 16;
        for (int round = 0; round < R; ++round){
          const char* rp = fastr + (size_t)round * REPSTRIDE + rbase;
          #pragma unroll
          for (int ks = 0; ks < 16; ++ks){
            const char* pa = rp + ks * 64;
            asm volatile("global_load_dwordx4 %0, %1, off sc0"
                         : "=v"(aF[ks]) : "v"(pa) : "memory");
          }
          asm volatile("s_waitcnt vmcnt(0)"
                       : "+v"(aF[0]),  "+v"(aF[1]),  "+v"(aF[2]),  "+v"(aF[3]),
                         "+v"(aF[4]),  "+v"(aF[5]),  "+v"(aF[6]),  "+v"(aF[7]),
                         "+v"(aF[8]),  "+v"(aF[9]),  "+v"(aF[10]), "+v"(aF[11]),
                         "+v"(aF[12]), "+v"(aF[13]), "+v"(aF[14]), "+v"(aF[15])
                       :: "memory");
          bool bad = false;
          #pragma unroll
          for (int ks = 0; ks < 16; ++ks) bad |= has_sent(aF[ks]);
          if (!__any(bad)){ got = true; break; }
          if (round + 1 < R) __builtin_amdgcn_s_sleep(4);  // ~0.1us spacing
        }
        if (!got && ++badsteps >= BADSTEP_LIMIT) localok = 0;  // sticky
      }
      if (!got){
        // 2a-TRUTH: r6-proven self-synchronizing sc0sc1 sentinel poll.
        // (fastpath producers write truth every step at system scope ->
        //  guaranteed to terminate; legacy path identical to r6.)
        int rounds = 0;
        while (true){
          if (rounds){
            if (rounds > 64) __builtin_amdgcn_s_sleep(8);
            else             __builtin_amdgcn_s_sleep(2);
          }
          ++rounds;
          #pragma unroll
          for (int ks = 0; ks < 16; ++ks){
            const char* pa = rowt + ks * 64;
            asm volatile("global_load_dwordx4 %0, %1, off sc0 sc1"
                         : "=v"(aF[ks]) : "v"(pa) : "memory");
          }
          asm volatile("s_waitcnt vmcnt(0)"
                       : "+v"(aF[0]),  "+v"(aF[1]),  "+v"(aF[2]),  "+v"(aF[3]),
                         "+v"(aF[4]),  "+v"(aF[5]),  "+v"(aF[6]),  "+v"(aF[7]),
                         "+v"(aF[8]),  "+v"(aF[9]),  "+v"(aF[10]), "+v"(aF[11]),
                         "+v"(aF[12]), "+v"(aF[13]), "+v"(aF[14]), "+v"(aF[15])
                       :: "memory");
          bool bad = false;
          #pragma unroll
          for (int ks = 0; ks < 16; ++ks) bad |= has_sent(aF[ks]);
          if (!__any(bad)) break;
        }
      }
      #pragma unroll
      for (int ks = 0; ks < 16; ++ks){
        half8 a  = aF[ks];
        half8 b0 = *(const half8*)&wlds[((size_t)(0 * 16 + ks) * 64 + l) * 8];
        half8 b1 = *(const half8*)&wlds[((size_t)(1 * 16 + ks) * 64 + l) * 8];
        half8 b2 = *(const half8*)&wlds[((size_t)(2 * 16 + ks) * 64 + l) * 8];
        aR = __builtin_amdgcn_mfma_f32_16x16x32_f16(a, b0, aR, 0, 0, 0);
        aZ = __builtin_amdgcn_mfma_f32_16x16x32_f16(a, b1, aZ, 0, 0, 0);
        aN = __builtin_amdgcn_mfma_f32_16x16x32_f16(a, b2, aN, 0, 0, 0);
      }
      // restore sentinels on consumed truth chunks (legacy reuse only)
      if (reuse){
        uintx4 sv = {0xFFFFFFFFu, 0xFFFFFFFFu, 0xFFFFFFFFu, 0xFFFFFFFFu};
        if (!fast || l15 < 8){
          #pragma unroll
          for (int ks = 0; ks < 16; ++ks){
            const char* pt = rowt + ks * 64;
            asm volatile("global_store_dwordx4 %0, %1, off sc0 sc1"
                         :: "v"(pt), "v"(sv) : "memory");
          }
        }
      }
    }

    // 3) gates + h update (f32 carry); mirrored quads duplicate harmlessly
    #pragma unroll
    for (int r = 0; r < 4; ++r){
      float rr = sigm(bf2f(xR[r]) + aR[r] + bhR);
      float zz = sigm(bf2f(xZ[r]) + aZ[r] + bhZ);
      float nn = tanh_c(bf2f(xN[r]) + rr * (aN[r] + bhN));
      float hn = (1.f - zz) * nn + zz * h[r];
      h[r] = (t < len[r]) ? hn : h[r];
    }

    // 4) intra-wave repack via LDS, then publish h(t)
    _Float16* scr = hscr + w * 256;
    if (!fast || quad < 2){
      #pragma unroll
      for (int r = 0; r < 4; ++r) scr[(locb + r) * 16 + l15] = (_Float16)h[r];
    }
    asm volatile("s_waitcnt lgkmcnt(0)" ::: "memory");   // wave-local DS order
    if (fastpath){
      // release: R replica sc0 stores (land in the shared XCD L2; consumer's
      // fresh-replica polls detect arrival) + 1 sc0sc1 truth store (escape
      // feed + K3). ALL fire-and-forget — no vmcnt, no flags, no atomics.
      if (l < 16){
        int bl = l >> 1;
        int hc = l & 1;
        half8 ch = *(const half8*)&scr[bl * 16 + hc * 8];
        const size_t coff = (size_t)(t & mask) * TSLOT + (size_t)grp * 8192
                          + (size_t)bl * 1024 + (size_t)g * 32 + (size_t)hc * 16;
        for (int rep = 0; rep < R; ++rep){
          const char* df = fastr + (size_t)rep * REPSTRIDE + coff;
          asm volatile("global_store_dwordx4 %0, %1, off sc0"
                       :: "v"(df), "v"(ch) : "memory");
        }
        const char* dt = truth + (size_t)(t & mask) * TSLOT
                       + (size_t)(grp * GRPB + bl) * 1024
                       + (size_t)g * 32 + (size_t)hc * 16;
        asm volatile("global_store_dwordx4 %0, %1, off sc0 sc1"
                     :: "v"(dt), "v"(ch) : "memory");
      }
    } else {
      const int pubN = fast ? 16 : 32;
      if (l < pubN){
        int bl = l >> 1;
        int hc = l & 1;
        half8 ch = *(const half8*)&scr[bl * 16 + hc * 8];
        int gbatch = fast ? (grp * GRPB + bl) : (w * 16 + bl);
        const char* dt = truth + (size_t)(t & mask) * TSLOT
                       + (size_t)gbatch * 1024 + (size_t)g * 32 + (size_t)hc * 16;
        asm volatile("global_store_dwordx4 %0, %1, off sc0 sc1"
                     :: "v"(dt), "v"(ch) : "memory");
      }
      // 5) coarse progress publish (reuse mode only), ordered after restores
      if (reuse && ((t & 7) == 7)){
        asm volatile("s_waitcnt vmcnt(0)" ::: "memory");
        if (l == 0){
          int pv = t + 1;
          const int* pp = fast ? (prog + 128 + grp * 32 + g) : (prog + w * 32 + g);
          asm volatile("global_store_dword %0, %1, off sc0 sc1"
                       :: "v"(pp), "v"(pv) : "memory");
        }
      }
    }
  }
}

// --- K3: logits + log_softmax from truth slot (Lmax-1). 64 blocks x 64. ---
__global__ __launch_bounds__(64) void gru_out(
    const char* __restrict__ truth, const int* __restrict__ lengths,
    const float* __restrict__ wout, const float* __restrict__ bout,
    float* __restrict__ out, int depth)
{
  const int b = blockIdx.x, l = threadIdx.x;
  const int Lmax = lengths[0];
  const _Float16* h = (const _Float16*)(truth
      + (size_t)((Lmax - 1) & (depth - 1)) * TSLOT + (size_t)b * 1024);
  half8 hv = *(const half8*)(h + l * 8);
  float p[NOUT];
  #pragma unroll
  for (int o = 0; o < NOUT; ++o){
    const float* wr = wout + o * HID + l * 8;
    float a = 0.f;
    #pragma unroll
    for (int i = 0; i < 8; ++i) a += wr[i] * (float)hv[i];
    #pragma unroll
    for (int d = 32; d >= 1; d >>= 1) a += __shfl_down(a, d, 64);
    p[o] = a;
  }
  if (l == 0){
    float lg[NOUT], m = -1e30f;
    #pragma unroll
    for (int o = 0; o < NOUT; ++o){
      float v = p[o] + bout[o];
      if (!(v == v)) v = -1.0f;
      lg[o] = v; m = fmaxf(m, v);
    }
    float ssum = 0.f;
    #pragma unroll
    for (int o = 0; o < NOUT; ++o) ssum += __expf(lg[o] - m);
    float ls = __logf(ssum);
    #pragma unroll
    for (int o = 0; o < NOUT; ++o) out[b * NOUT + o] = lg[o] - m - ls;
  }
}

extern "C" void kernel_launch(void* const* d_in, const int* in_sizes, int n_in,
                              void* d_out, int out_size, void* d_ws, size_t ws_size,
                              hipStream_t stream) {
  (void)in_sizes; (void)n_in; (void)out_size;
  const int*   seq     = (const int*)d_in[0];
  const int*   lengths = (const int*)d_in[1];
  const float* emb     = (const float*)d_in[2];
  const float* w_ih    = (const float*)d_in[3];
  const float* w_hh    = (const float*)d_in[4];
  const float* b_ih    = (const float*)d_in[5];
  const float* b_hh    = (const float*)d_in[6];
  const float* w_out   = (const float*)d_in[7];
  const float* b_out   = (const float*)d_in[8];
  float*       outp    = (float*)d_out;

  size_t avail = (ws_size > (size_t)XG_BYTES + 32768)
               ? ws_size - (size_t)XG_BYTES - 32768 : 0;
  const size_t T512 = 512ull * (size_t)TSLOT;      // 32 MB (truth, depth 512)

  // Prefer fastpath: truth depth=512 (no reuse) + R replica planes (R x 32MB).
  int depth = 0, R = 0;
  for (int r = 4; r >= 2; --r){
    if (T512 + (size_t)r * T512 <= avail){ depth = 512; R = r; break; }
  }
  size_t fast_bytes;
  if (R >= 2){
    fast_bytes = (size_t)R * T512;
  } else {
    // legacy sizing (r6): truth+fast pair, depth power of two, reuse if <512
    depth = 16;
    while (depth < 512 && ((size_t)(depth << 1) * RING2) <= avail) depth <<= 1;
    fast_bytes = (size_t)depth * TSLOT;
  }

  char* ws = (char*)d_ws;
  ushort_t* xg    = (ushort_t*)ws;                                 // 100,663,296 B
  char*     truth = ws + XG_BYTES;                                 // depth*64KB
  char*     fastr = truth + (size_t)depth * TSLOT;
  int*      prog  = (int*)(fastr + fast_bytes);                    // 768 ints

  size_t ring_bytes = (size_t)depth * TSLOT + fast_bytes;
  int init_blocks = (int)(ring_bytes / 4096);                      // exact: 64KB multiples

  gru_init<<<init_blocks, 256, 0, stream>>>(truth, prog);
  dim3 g1(SEQL, G3 / 64);
  gru_xgates<<<g1, 256, 0, stream>>>(seq, emb, w_ih, b_ih, xg);
  gru_rec<<<256, 256, 0, stream>>>(xg, w_hh, b_hh, lengths, truth, fastr, prog,
                                   depth, R);
  gru_out<<<BATCH, 64, 0, stream>>>(truth, lengths, w_out, b_out, outp, depth);
}